// Round 10
// baseline (262.661 us; speedup 1.0000x reference)
//
#include <hip/hip_runtime.h>

#define N_NODES 100000
#define N_HEDGES 25000
#define N_EDGES 1000000
#define NG 64
#define HD 64

// binned CSR build params
#define EB_SH 8
#define EB_NB 98
#define EB_CAP 12000
#define NB_SH 9
#define NB_NB 196
#define NB_CAP 6200
#define TILE 4096
#define TPS 245
#define ENC_F4 ((N_NODES + N_HEDGES) * 16)

typedef __attribute__((ext_vector_type(4))) float f4;
typedef __attribute__((ext_vector_type(4))) unsigned short us4;
typedef __attribute__((ext_vector_type(8))) unsigned short us8;
typedef __attribute__((ext_vector_type(8))) short s8b;   // MFMA bf16 A/B fragment

__device__ __forceinline__ unsigned short f2bf(float f) {
    unsigned int u = __float_as_uint(f);
    unsigned int r = (u + 0x7FFFu + ((u >> 16) & 1u)) >> 16;  // RNE
    return (unsigned short)r;
}
__device__ __forceinline__ float bf2f(unsigned short h) {
    return __uint_as_float((unsigned int)h << 16);
}
__device__ __forceinline__ us4 f4_to_bf4(f4 v) {
    us4 h;
    h[0] = f2bf(v[0]); h[1] = f2bf(v[1]); h[2] = f2bf(v[2]); h[3] = f2bf(v[3]);
    return h;
}

// ---------------- prep: W->Wt bf16 transpose (blocks 0-3) + zero (rest) ----------------
__global__ __launch_bounds__(256) void prep(
    const float* __restrict__ W1lE, const float* __restrict__ W1rE,
    const float* __restrict__ W1lN, const float* __restrict__ W1rN,
    const float* __restrict__ W2lE, const float* __restrict__ W2rE,
    const float* __restrict__ W2lN, const float* __restrict__ W2rN,
    unsigned short* __restrict__ WtH, int* __restrict__ zbase, int zn) {
    int b = blockIdx.x, t = threadIdx.x;
    if (b < 4) {
        const float *Wl, *Wr;
        switch (b) {
            case 0: Wl = W1lE; Wr = W1rE; break;
            case 1: Wl = W1lN; Wr = W1rN; break;
            case 2: Wl = W2lE; Wr = W2rE; break;
            default: Wl = W2lN; Wr = W2rN; break;
        }
        unsigned short* o = WtH + b * 8192;
        for (int idx = t; idx < 8192; idx += 256) {
            int c = idx >> 7, k = idx & 127;
            float v = (k < 64) ? Wl[k * 64 + c] : Wr[(k - 64) * 64 + c];
            o[c * 128 + k] = f2bf(v);  // Wt[col][k]: B^T layout
        }
    } else {
        int i = (b - 4) * 256 + t;
        if (i < zn) zbase[i] = 0;
    }
}

// ---------------- pass 1: LDS-binned scatter + fused encoder (chunk-major bf16 out) ----------------
// feature layout: x[c][row][8] for c = 0..7 (chunk c holds feats c*8..c*8+7)
__global__ __launch_bounds__(256) void bin_encode(
    const int* __restrict__ n2e_src, const int* __restrict__ n2e_dst,
    const int* __restrict__ e2n_src, const int* __restrict__ e2n_dst,
    int* __restrict__ binE, int* __restrict__ binN,
    int* __restrict__ gcntE, int* __restrict__ gcntN,
    const float* __restrict__ node_x, const float* __restrict__ edge_x,
    const float* __restrict__ Wn, const float* __restrict__ bn,
    const float* __restrict__ We, const float* __restrict__ be,
    unsigned short* __restrict__ xnC, unsigned short* __restrict__ xeC) {
    __shared__ int pairsL[TILE];
    __shared__ int hist[256], scanv[256], start[256], curs[256], gbase[256];
    int t = threadIdx.x;
    if ((int)blockIdx.x >= 2 * TPS) {
        int i4 = ((int)blockIdx.x - 2 * TPS) * 256 + t;
        if (i4 < N_NODES * 16) {
            int row = i4 >> 4, q = i4 & 15;
            int cc = q >> 1, hh = (q & 1) * 4;
            f4 wn = *(const f4*)(Wn + cc * 8 + hh);
            f4 bnv = *(const f4*)(bn + cc * 8 + hh);
            float xv = node_x[row];
            f4 v;
#pragma unroll
            for (int c = 0; c < 4; c++) v[c] = fmaxf(xv * wn[c] + bnv[c], 0.f);
            *(us4*)(xnC + ((long)cc * N_NODES + row) * 8 + hh) = f4_to_bf4(v);
        } else if (i4 < ENC_F4) {
            int j = i4 - N_NODES * 16;
            int row = j >> 4, q = j & 15;
            int cc = q >> 1, hh = (q & 1) * 4;
            f4 w0 = *(const f4*)(We + cc * 8 + hh);
            f4 w1 = *(const f4*)(We + HD + cc * 8 + hh);
            f4 bev = *(const f4*)(be + cc * 8 + hh);
            float x0 = edge_x[2 * row], x1 = edge_x[2 * row + 1];
            f4 v;
#pragma unroll
            for (int c = 0; c < 4; c++) v[c] = fmaxf(x0 * w0[c] + x1 * w1[c] + bev[c], 0.f);
            *(us4*)(xeC + ((long)cc * N_HEDGES + row) * 8 + hh) = f4_to_bf4(v);
        }
        return;
    }
    int side = (int)blockIdx.x >= TPS;
    int lb = blockIdx.x - (side ? TPS : 0);
    const int* dsts = side ? e2n_dst : n2e_dst;
    const int* srcs = side ? e2n_src : n2e_src;
    int NB = side ? NB_NB : EB_NB;
    int SH = side ? NB_SH : EB_SH;
    int CAP = side ? NB_CAP : EB_CAP;
    int* bins = side ? binN : binE;
    int* gcnt = side ? gcntN : gcntE;
    int base = lb * TILE;

    hist[t] = 0;
    __syncthreads();

    int pair[16], buck[16];
#pragma unroll
    for (int k = 0; k < 16; k++) {
        int e = base + k * 256 + t;
        if (e < N_EDGES) {
            int d = dsts[e];
            int s = srcs[e];
            buck[k] = d >> SH;
            pair[k] = ((d & ((1 << SH) - 1)) << 17) | s;
            atomicAdd(&hist[buck[k]], 1);
        } else buck[k] = -1;
    }
    __syncthreads();
    int v = hist[t];
    scanv[t] = v;
    __syncthreads();
    for (int o = 1; o < 256; o <<= 1) {
        int x = (t >= o) ? scanv[t - o] : 0;
        __syncthreads();
        scanv[t] += x;
        __syncthreads();
    }
    start[t] = scanv[t] - v;
    curs[t] = scanv[t] - v;
    if (t < NB && v > 0) gbase[t] = t * CAP + atomicAdd(&gcnt[t], v);
    __syncthreads();
    int total = scanv[255];
#pragma unroll
    for (int k = 0; k < 16; k++) {
        if (buck[k] >= 0) {
            int slot = atomicAdd(&curs[buck[k]], 1);
            pairsL[slot] = pair[k];
        }
    }
    __syncthreads();
    for (int i = t; i < total; i += 256) {
        int lo = 0, hi = NB - 1;
        while (lo < hi) { int mid = (lo + hi + 1) >> 1; if (start[mid] <= i) lo = mid; else hi = mid - 1; }
        bins[gbase[lo] + (i - start[lo])] = pairsL[i];
    }
}

// ---------------- pass 2: per-bucket fine CSR fill (E-side u32 src, N-side u16 src) ----------------
__global__ __launch_bounds__(512) void fine_fill(
    const int* __restrict__ binE, const int* __restrict__ binN,
    const int* __restrict__ gcntE, const int* __restrict__ gcntN,
    int* __restrict__ off, int* __restrict__ deg,
    int* __restrict__ srtE, unsigned short* __restrict__ srtN) {
    __shared__ int hist[512], scanv[512];
    int t = threadIdx.x;
    int side = (int)blockIdx.x >= EB_NB;
    int b = blockIdx.x - (side ? EB_NB : 0);
    int NROWS = side ? 512 : 256;
    int CAP = side ? NB_CAP : EB_CAP;
    const int* bins = (side ? binN : binE) + (long)b * CAP;
    int cnt_b = (side ? gcntN : gcntE)[b];
    int rowbase = side ? (N_HEDGES + b * 512) : b * 256;
    int nrows = (side ? N_NODES : N_HEDGES) - (side ? b * 512 : b * 256);
    if (nrows > NROWS) nrows = NROWS;
    int* srtEb = srtE + (long)b * CAP;
    unsigned short* srtNb = srtN + (long)b * CAP;

    hist[t] = 0;
    __syncthreads();
    for (int i = t; i < cnt_b; i += 512) atomicAdd(&hist[bins[i] >> 17], 1);
    __syncthreads();
    int v = hist[t];
    scanv[t] = v;
    __syncthreads();
    for (int o = 1; o < 512; o <<= 1) {
        int x = (t >= o) ? scanv[t - o] : 0;
        __syncthreads();
        scanv[t] += x;
        __syncthreads();
    }
    int excl = scanv[t] - v;
    if (t < nrows) { off[rowbase + t] = b * CAP + excl; deg[rowbase + t] = v; }
    scanv[t] = excl;
    __syncthreads();
    for (int i = t; i < cnt_b; i += 512) {
        int p = bins[i];
        int pos = atomicAdd(&scanv[p >> 17], 1);
        if (side) srtNb[pos] = (unsigned short)(p & 0x1FFFF);  // hyperedge ids < 25000
        else srtEb[pos] = p & 0x1FFFF;                         // node ids < 100000
    }
}

// ---------------- gather-mean, chunk-major, XCD-pinned (blockIdx&7 = chunk) ----------------
// wave = 8 rows x 8 edge-sublanes; per-lane us8 (16B = 8 feats of one chunk).
// Per-XCD working set: 1.6MB (node slice) + 0.4MB (edge slice) -> L2-resident.
__global__ __launch_bounds__(256) void gather_cm(
    const unsigned short* __restrict__ xnC, const unsigned short* __restrict__ xeC,
    const int* __restrict__ off, const int* __restrict__ deg,
    const int* __restrict__ srtE, const unsigned short* __restrict__ srtN,
    unsigned short* __restrict__ aggEC, unsigned short* __restrict__ aggNC) {
    int t = threadIdx.x;
    int lane = t & 63, w = t >> 6;
    int c = blockIdx.x & 7;          // feature chunk == target XCD
    int bg = blockIdx.x >> 3;
    int NBG = gridDim.x >> 3;
    int sub = lane & 7;              // edge sublane
    int rg = lane >> 3;              // row slot in group
    const int EG = N_HEDGES / 8;     // 3125 edge-side groups (exact)
    const int NGRP = (N_HEDGES + N_NODES) / 8;  // 15625 (exact)
    const unsigned short* srcN = xnC + (long)c * (N_NODES * 8);
    const unsigned short* srcE = xeC + (long)c * (N_HEDGES * 8);

    for (int g0 = bg * 4 + w; g0 < NGRP; g0 += NBG * 4) {
        int r = g0 * 8 + rg;
        int lo = off[r], dg = deg[r];
        f4 a0 = {0.f, 0.f, 0.f, 0.f}, a1 = a0, b0 = a0, b1 = a0;
        if (g0 < EG) {
            // hyperedge rows gather node features (u32 srcs)
            int j = sub;
            for (; j + 8 < dg; j += 16) {
                int s0 = srtE[lo + j];
                int s1 = srtE[lo + j + 8];
                us8 h0 = *(const us8*)(srcN + (long)s0 * 8);
                us8 h1 = *(const us8*)(srcN + (long)s1 * 8);
#pragma unroll
                for (int i = 0; i < 4; i++) {
                    a0[i] += bf2f(h0[i]); a1[i] += bf2f(h0[i + 4]);
                    b0[i] += bf2f(h1[i]); b1[i] += bf2f(h1[i + 4]);
                }
            }
            if (j < dg) {
                int s = srtE[lo + j];
                us8 h = *(const us8*)(srcN + (long)s * 8);
#pragma unroll
                for (int i = 0; i < 4; i++) { a0[i] += bf2f(h[i]); a1[i] += bf2f(h[i + 4]); }
            }
        } else {
            // node rows gather hyperedge features (u16 srcs)
            int j = sub;
            for (; j + 8 < dg; j += 16) {
                int s0 = srtN[lo + j];
                int s1 = srtN[lo + j + 8];
                us8 h0 = *(const us8*)(srcE + (long)s0 * 8);
                us8 h1 = *(const us8*)(srcE + (long)s1 * 8);
#pragma unroll
                for (int i = 0; i < 4; i++) {
                    a0[i] += bf2f(h0[i]); a1[i] += bf2f(h0[i + 4]);
                    b0[i] += bf2f(h1[i]); b1[i] += bf2f(h1[i + 4]);
                }
            }
            if (j < dg) {
                int s = srtN[lo + j];
                us8 h = *(const us8*)(srcE + (long)s * 8);
#pragma unroll
                for (int i = 0; i < 4; i++) { a0[i] += bf2f(h[i]); a1[i] += bf2f(h[i + 4]); }
            }
        }
        a0 += b0; a1 += b1;
#pragma unroll
        for (int m = 1; m <= 4; m <<= 1) {
#pragma unroll
            for (int i = 0; i < 4; i++) {
                a0[i] += __shfl_xor(a0[i], m);
                a1[i] += __shfl_xor(a1[i], m);
            }
        }
        if (sub == 0) {
            float invd = 1.f / (float)(dg > 1 ? dg : 1);
            us8 o;
            us4 p0 = f4_to_bf4(a0 * invd), p1 = f4_to_bf4(a1 * invd);
#pragma unroll
            for (int i = 0; i < 4; i++) { o[i] = p0[i]; o[i + 4] = p1[i]; }
            if (g0 < EG) *(us8*)(aggEC + ((long)c * N_HEDGES + r) * 8) = o;
            else *(us8*)(aggNC + ((long)c * N_NODES + (r - N_HEDGES)) * 8) = o;
        }
    }
}

// ---------------- combine via MFMA (chunk-major in/out) ----------------
__global__ __launch_bounds__(256) void combine_mfma(
    const unsigned short* __restrict__ aggEC, const unsigned short* __restrict__ xeC,
    const unsigned short* __restrict__ aggNC, const unsigned short* __restrict__ xnC,
    const unsigned short* __restrict__ WtE, const float* __restrict__ blE,
    const unsigned short* __restrict__ WtN, const float* __restrict__ blN,
    unsigned short* __restrict__ outEC, unsigned short* __restrict__ outNC, int gbE) {
    __shared__ unsigned short sA[64][136];
    __shared__ unsigned short sW[64][136];
    int t = threadIdx.x;
    const unsigned short *aggC, *xdstC, *Wt;
    const float* bl;
    unsigned short* outC;
    int rows, row0;
    if ((int)blockIdx.x < gbE) {
        aggC = aggEC; xdstC = xeC; Wt = WtE; bl = blE; outC = outEC;
        rows = N_HEDGES; row0 = blockIdx.x * 64;
    } else {
        aggC = aggNC; xdstC = xnC; Wt = WtN; bl = blN; outC = outNC;
        rows = N_NODES; row0 = (blockIdx.x - gbE) * 64;
    }

#pragma unroll
    for (int q = 0; q < 4; q++) {
        int idx = q * 256 + t;
        int cw = idx >> 4, ch = idx & 15;
        *(us8*)&sW[cw][ch * 8] = *(const us8*)(Wt + cw * 128 + ch * 8);
    }
#pragma unroll
    for (int q = 0; q < 4; q++) {
        int idx = q * 256 + t;
        int r = idx >> 4, ch = idx & 15;
        int gr = row0 + r;
        us8 v;
        if (gr < rows) {
            v = (ch < 8) ? *(const us8*)(aggC + ((long)ch * rows + gr) * 8)
                         : *(const us8*)(xdstC + ((long)(ch - 8) * rows + gr) * 8);
        } else {
            v = (us8){0, 0, 0, 0, 0, 0, 0, 0};
        }
        *(us8*)&sA[r][ch * 8] = v;
    }
    __syncthreads();

    int lane = t & 63, w = t >> 6;
    int m0 = w * 16;
    int l15 = lane & 15, quad = lane >> 4;
    f4 acc[4];
#pragma unroll
    for (int ct = 0; ct < 4; ct++) {
        float b = bl[ct * 16 + l15];
        acc[ct] = (f4){b, b, b, b};
    }
#pragma unroll
    for (int kb = 0; kb < 4; kb++) {
        s8b a = *(const s8b*)&sA[m0 + l15][kb * 32 + quad * 8];
#pragma unroll
        for (int ct = 0; ct < 4; ct++) {
            s8b bfr = *(const s8b*)&sW[ct * 16 + l15][kb * 32 + quad * 8];
            acc[ct] = __builtin_amdgcn_mfma_f32_16x16x32_bf16(a, bfr, acc[ct], 0, 0, 0);
        }
    }
#pragma unroll
    for (int ct = 0; ct < 4; ct++) {
#pragma unroll
        for (int r = 0; r < 4; r++) {
            int gr = row0 + m0 + quad * 4 + r;
            if (gr < rows) {
                int col = ct * 16 + l15;
                outC[((long)(col >> 3) * rows + gr) * 8 + (col & 7)] = f2bf(fmaxf(acc[ct][r], 0.f));
            }
        }
    }
}

// ---------------- parallel pooling from chunk-major bf16 feats ----------------
__device__ __forceinline__ int lower_bound_dev(const int* arr, int n, int key) {
    int lo = 0, hi = n;
    while (lo < hi) { int mid = (lo + hi) >> 1; if (arr[mid] < key) lo = mid + 1; else hi = mid; }
    return lo;
}

#define PB_N 8
#define PB_E 2
__global__ __launch_bounds__(256) void pool_bf(
    const unsigned short* __restrict__ xnC, const unsigned short* __restrict__ xeC,
    const int* __restrict__ node_batch, const int* __restrict__ edge_batch,
    float* __restrict__ poolN, float* __restrict__ poolE) {
    __shared__ float sp[4][64];
    int b = blockIdx.x;
    const unsigned short* x; const int* batch; float* pool; int n, g, part, P;
    if (b < NG * PB_N) { x = xnC; batch = node_batch; pool = poolN; n = N_NODES; g = b / PB_N; part = b % PB_N; P = PB_N; }
    else { b -= NG * PB_N; x = xeC; batch = edge_batch; pool = poolE; n = N_HEDGES; g = b / PB_E; part = b % PB_E; P = PB_E; }
    int s = lower_bound_dev(batch, n, g);
    int e = lower_bound_dev(batch, n, g + 1);
    int len = e - s;
    int start = s + (int)(((long)len * part) / P);
    int end = s + (int)(((long)len * (part + 1)) / P);
    int lane = threadIdx.x & 63, w = threadIdx.x >> 6;
    int cc = lane & 7, rw = lane >> 3;  // chunk x row-slot
    const unsigned short* xc = x + (long)cc * n * 8;
    f4 a0 = {0.f, 0.f, 0.f, 0.f}, a1 = a0;
    for (int r = start + w * 8 + rw; r < end; r += 32) {
        us8 h = *(const us8*)(xc + (long)r * 8);
#pragma unroll
        for (int i = 0; i < 4; i++) { a0[i] += bf2f(h[i]); a1[i] += bf2f(h[i + 4]); }
    }
#pragma unroll
    for (int m = 8; m <= 32; m <<= 1) {
#pragma unroll
        for (int i = 0; i < 4; i++) {
            a0[i] += __shfl_xor(a0[i], m);
            a1[i] += __shfl_xor(a1[i], m);
        }
    }
    if (rw == 0) {
        *(f4*)&sp[w][cc * 8] = a0;
        *(f4*)&sp[w][cc * 8 + 4] = a1;
    }
    __syncthreads();
    if (threadIdx.x < 64) {
        int tt = threadIdx.x;
        float v = sp[0][tt] + sp[1][tt] + sp[2][tt] + sp[3][tt];
        if (v != 0.f) atomicAdd(&pool[g * HD + tt], v);
    }
}

// ---------------- final readout ----------------
__global__ __launch_bounds__(64) void final_readout(
    const float* __restrict__ poolN, const float* __restrict__ poolE,
    const int* __restrict__ node_batch, const int* __restrict__ edge_batch,
    const float* __restrict__ Wout, const float* __restrict__ bout,
    float* __restrict__ out) {
    __shared__ float inv[2];
    int g = blockIdx.x, t = threadIdx.x;
    if (t < 2) {
        const int* arr = t ? edge_batch : node_batch;
        int n = t ? N_HEDGES : N_NODES;
        int lo = lower_bound_dev(arr, n, g);
        int hi = lower_bound_dev(arr, n, g + 1);
        int c = hi - lo;
        inv[t] = 1.f / (float)(c > 1 ? c : 1);
    }
    __syncthreads();
    if (t < 32) {
        float iN = inv[0], iE = inv[1];
        float s = bout[t];
#pragma unroll 8
        for (int k = 0; k < HD; k++)
            s += poolN[g * HD + k] * iN * Wout[k * 32 + t]
               + poolE[g * HD + k] * iE * Wout[(HD + k) * 32 + t];
        out[g * 32 + t] = s;
    }
}

extern "C" void kernel_launch(void* const* d_in, const int* in_sizes, int n_in,
                              void* d_out, int out_size, void* d_ws, size_t ws_size,
                              hipStream_t stream) {
    const float* node_x = (const float*)d_in[0];
    const float* edge_x = (const float*)d_in[1];
    const int* n2e_src = (const int*)d_in[2];
    const int* n2e_dst = (const int*)d_in[3];
    const int* e2n_src = (const int*)d_in[4];
    const int* e2n_dst = (const int*)d_in[5];
    const int* node_batch = (const int*)d_in[6];
    const int* edge_batch = (const int*)d_in[7];
    const float* Wn = (const float*)d_in[8];
    const float* bn = (const float*)d_in[9];
    const float* We = (const float*)d_in[10];
    const float* be = (const float*)d_in[11];
    const float* W1l_n2e = (const float*)d_in[12];
    const float* b1l_n2e = (const float*)d_in[13];
    const float* W1r_n2e = (const float*)d_in[14];
    const float* W1l_e2n = (const float*)d_in[15];
    const float* b1l_e2n = (const float*)d_in[16];
    const float* W1r_e2n = (const float*)d_in[17];
    const float* W2l_n2e = (const float*)d_in[18];
    const float* b2l_n2e = (const float*)d_in[19];
    const float* W2r_n2e = (const float*)d_in[20];
    const float* W2l_e2n = (const float*)d_in[21];
    const float* b2l_e2n = (const float*)d_in[22];
    const float* W2r_e2n = (const float*)d_in[23];
    const float* Wout = (const float*)d_in[24];
    const float* bout = (const float*)d_in[25];
    float* out = (float*)d_out;

    // ---- workspace layout (chunk-major bf16 features; ~66 MB) ----
    unsigned short* xnC0 = (unsigned short*)d_ws;      // [8][100000][8]
    unsigned short* xeC0 = xnC0 + N_NODES * HD;        // [8][25000][8]
    unsigned short* xnC1 = xeC0 + N_HEDGES * HD;
    unsigned short* xeC1 = xnC1 + N_NODES * HD;
    unsigned short* aggNC = xeC1 + N_HEDGES * HD;
    unsigned short* aggEC = aggNC + N_NODES * HD;
    unsigned short* WtH = aggEC + N_HEDGES * HD;       // 4 x [64][128]
    float* poolN = (float*)(WtH + 4 * 8192);           // 4096
    float* poolE = poolN + NG * HD;                    // 4096
    int* gcntE = (int*)(poolE + NG * HD);              // 98
    int* gcntN = gcntE + EB_NB;                        // 196
    int* off = gcntN + NB_NB;                          // 125000
    int* deg = off + (N_HEDGES + N_NODES);             // 125000
    int* binE = deg + (N_HEDGES + N_NODES);            // 1,176,000
    int* binN = binE + EB_NB * EB_CAP;                 // 1,215,200
    int* srtE = binN + NB_NB * NB_CAP;                 // 1,176,000 u32
    unsigned short* srtN = (unsigned short*)(srtE + EB_NB * EB_CAP);  // 1,215,200 u16

    const int Bt = 256;

    // 1) prep: Wt conversion + zero pools/cursors
    int zn = 2 * NG * HD + EB_NB + NB_NB;
    prep<<<4 + (zn + Bt - 1) / Bt, Bt, 0, stream>>>(
        W1l_n2e, W1r_n2e, W1l_e2n, W1r_e2n,
        W2l_n2e, W2r_n2e, W2l_e2n, W2r_e2n,
        WtH, (int*)poolN, zn);

    // 2) binning + encoder
    int encBlocks = (ENC_F4 + Bt - 1) / Bt;
    bin_encode<<<2 * TPS + encBlocks, Bt, 0, stream>>>(
        n2e_src, n2e_dst, e2n_src, e2n_dst, binE, binN, gcntE, gcntN,
        node_x, edge_x, Wn, bn, We, be, xnC0, xeC0);

    // 3) fine CSR fill
    fine_fill<<<EB_NB + NB_NB, 512, 0, stream>>>(binE, binN, gcntE, gcntN,
                                                 off, deg, srtE, srtN);

    int gbE = (N_HEDGES + 63) / 64;  // 391
    int gbN = (N_NODES + 63) / 64;   // 1563
    int gridC = gbE + gbN;

    // 4-5) layer 1
    gather_cm<<<2048, Bt, 0, stream>>>(xnC0, xeC0, off, deg, srtE, srtN, aggEC, aggNC);
    combine_mfma<<<gridC, Bt, 0, stream>>>(aggEC, xeC0, aggNC, xnC0,
                                           WtH, b1l_n2e, WtH + 8192, b1l_e2n,
                                           xeC1, xnC1, gbE);

    // 6-7) layer 2
    gather_cm<<<2048, Bt, 0, stream>>>(xnC1, xeC1, off, deg, srtE, srtN, aggEC, aggNC);
    combine_mfma<<<gridC, Bt, 0, stream>>>(aggEC, xeC1, aggNC, xnC1,
                                           WtH + 16384, b2l_n2e, WtH + 24576, b2l_e2n,
                                           xeC0, xnC0, gbE);

    // 8) pooling
    pool_bf<<<NG * PB_N + NG * PB_E, Bt, 0, stream>>>(xnC0, xeC0, node_batch, edge_batch, poolN, poolE);

    // 9) readout
    final_readout<<<NG, 64, 0, stream>>>(poolN, poolE, node_batch, edge_batch, Wout, bout, out);
}

// Round 11
// 201.696 us; speedup vs baseline: 1.3023x; 1.3023x over previous
//
#include <hip/hip_runtime.h>

#define N_NODES 100000
#define N_HEDGES 25000
#define N_EDGES 1000000
#define NG 64
#define HD 64

// binned CSR build params
#define EB_SH 8
#define EB_NB 98
#define EB_CAP 12000
#define NB_SH 9
#define NB_NB 196
#define NB_CAP 6200
#define TILE 4096
#define TPS 245
#define ENC_F4 ((N_NODES + N_HEDGES) * 16)

typedef __attribute__((ext_vector_type(4))) float f4;
typedef __attribute__((ext_vector_type(4))) unsigned short us4;
typedef __attribute__((ext_vector_type(8))) unsigned short us8;
typedef __attribute__((ext_vector_type(8))) short s8b;   // MFMA bf16 A/B fragment

__device__ __forceinline__ unsigned short f2bf(float f) {
    unsigned int u = __float_as_uint(f);
    unsigned int r = (u + 0x7FFFu + ((u >> 16) & 1u)) >> 16;  // RNE
    return (unsigned short)r;
}
__device__ __forceinline__ float bf2f(unsigned short h) {
    return __uint_as_float((unsigned int)h << 16);
}
__device__ __forceinline__ us4 f4_to_bf4(f4 v) {
    us4 h;
    h[0] = f2bf(v[0]); h[1] = f2bf(v[1]); h[2] = f2bf(v[2]); h[3] = f2bf(v[3]);
    return h;
}

// ---------------- prep: W->Wt bf16 transpose (blocks 0-3) + zero (rest) ----------------
__global__ __launch_bounds__(256) void prep(
    const float* __restrict__ W1lE, const float* __restrict__ W1rE,
    const float* __restrict__ W1lN, const float* __restrict__ W1rN,
    const float* __restrict__ W2lE, const float* __restrict__ W2rE,
    const float* __restrict__ W2lN, const float* __restrict__ W2rN,
    unsigned short* __restrict__ WtH, int* __restrict__ zbase, int zn) {
    int b = blockIdx.x, t = threadIdx.x;
    if (b < 4) {
        const float *Wl, *Wr;
        switch (b) {
            case 0: Wl = W1lE; Wr = W1rE; break;
            case 1: Wl = W1lN; Wr = W1rN; break;
            case 2: Wl = W2lE; Wr = W2rE; break;
            default: Wl = W2lN; Wr = W2rN; break;
        }
        unsigned short* o = WtH + b * 8192;
        for (int idx = t; idx < 8192; idx += 256) {
            int c = idx >> 7, k = idx & 127;
            float v = (k < 64) ? Wl[k * 64 + c] : Wr[(k - 64) * 64 + c];
            o[c * 128 + k] = f2bf(v);  // Wt[col][k]: B^T layout
        }
    } else {
        int i = (b - 4) * 256 + t;
        if (i < zn) zbase[i] = 0;
    }
}

// ---------------- pass 1: LDS-binned scatter + fused encoder (row-major bf16 out) ----------------
__global__ __launch_bounds__(256) void bin_encode(
    const int* __restrict__ n2e_src, const int* __restrict__ n2e_dst,
    const int* __restrict__ e2n_src, const int* __restrict__ e2n_dst,
    int* __restrict__ binE, int* __restrict__ binN,
    int* __restrict__ gcntE, int* __restrict__ gcntN,
    const float* __restrict__ node_x, const float* __restrict__ edge_x,
    const float* __restrict__ Wn, const float* __restrict__ bn,
    const float* __restrict__ We, const float* __restrict__ be,
    unsigned short* __restrict__ xnH, unsigned short* __restrict__ xeH) {
    __shared__ int pairsL[TILE];
    __shared__ int hist[256], scanv[256], start[256], curs[256], gbase[256];
    int t = threadIdx.x;
    if ((int)blockIdx.x >= 2 * TPS) {
        int i4 = ((int)blockIdx.x - 2 * TPS) * 256 + t;
        if (i4 < N_NODES * 16) {
            int row = i4 >> 4, fq = i4 & 15;
            f4 wn = *(const f4*)(Wn + fq * 4);
            f4 bnv = *(const f4*)(bn + fq * 4);
            float xv = node_x[row];
            f4 v;
#pragma unroll
            for (int c = 0; c < 4; c++) v[c] = fmaxf(xv * wn[c] + bnv[c], 0.f);
            *(us4*)(xnH + (long)i4 * 4) = f4_to_bf4(v);
        } else if (i4 < ENC_F4) {
            int j = i4 - N_NODES * 16;
            int row = j >> 4, fq = j & 15;
            f4 w0 = *(const f4*)(We + fq * 4);
            f4 w1 = *(const f4*)(We + HD + fq * 4);
            f4 bev = *(const f4*)(be + fq * 4);
            float x0 = edge_x[2 * row], x1 = edge_x[2 * row + 1];
            f4 v;
#pragma unroll
            for (int c = 0; c < 4; c++) v[c] = fmaxf(x0 * w0[c] + x1 * w1[c] + bev[c], 0.f);
            *(us4*)(xeH + (long)j * 4) = f4_to_bf4(v);
        }
        return;
    }
    int side = (int)blockIdx.x >= TPS;
    int lb = blockIdx.x - (side ? TPS : 0);
    const int* dsts = side ? e2n_dst : n2e_dst;
    const int* srcs = side ? e2n_src : n2e_src;
    int NB = side ? NB_NB : EB_NB;
    int SH = side ? NB_SH : EB_SH;
    int CAP = side ? NB_CAP : EB_CAP;
    int* bins = side ? binN : binE;
    int* gcnt = side ? gcntN : gcntE;
    int base = lb * TILE;

    hist[t] = 0;
    __syncthreads();

    int pair[16], buck[16];
#pragma unroll
    for (int k = 0; k < 16; k++) {
        int e = base + k * 256 + t;
        if (e < N_EDGES) {
            int d = dsts[e];
            int s = srcs[e];
            buck[k] = d >> SH;
            pair[k] = ((d & ((1 << SH) - 1)) << 17) | s;
            atomicAdd(&hist[buck[k]], 1);
        } else buck[k] = -1;
    }
    __syncthreads();
    int v = hist[t];
    scanv[t] = v;
    __syncthreads();
    for (int o = 1; o < 256; o <<= 1) {
        int x = (t >= o) ? scanv[t - o] : 0;
        __syncthreads();
        scanv[t] += x;
        __syncthreads();
    }
    start[t] = scanv[t] - v;
    curs[t] = scanv[t] - v;
    if (t < NB && v > 0) gbase[t] = t * CAP + atomicAdd(&gcnt[t], v);
    __syncthreads();
    int total = scanv[255];
#pragma unroll
    for (int k = 0; k < 16; k++) {
        if (buck[k] >= 0) {
            int slot = atomicAdd(&curs[buck[k]], 1);
            pairsL[slot] = pair[k];
        }
    }
    __syncthreads();
    for (int i = t; i < total; i += 256) {
        int lo = 0, hi = NB - 1;
        while (lo < hi) { int mid = (lo + hi + 1) >> 1; if (start[mid] <= i) lo = mid; else hi = mid - 1; }
        bins[gbase[lo] + (i - start[lo])] = pairsL[i];
    }
}

// ---------------- pass 2: per-bucket fine CSR fill (E-side u32 src, N-side u16 src) ----------------
__global__ __launch_bounds__(512) void fine_fill(
    const int* __restrict__ binE, const int* __restrict__ binN,
    const int* __restrict__ gcntE, const int* __restrict__ gcntN,
    int* __restrict__ off, int* __restrict__ deg,
    int* __restrict__ srtE, unsigned short* __restrict__ srtN) {
    __shared__ int hist[512], scanv[512];
    int t = threadIdx.x;
    int side = (int)blockIdx.x >= EB_NB;
    int b = blockIdx.x - (side ? EB_NB : 0);
    int NROWS = side ? 512 : 256;
    int CAP = side ? NB_CAP : EB_CAP;
    const int* bins = (side ? binN : binE) + (long)b * CAP;
    int cnt_b = (side ? gcntN : gcntE)[b];
    int rowbase = side ? (N_HEDGES + b * 512) : b * 256;
    int nrows = (side ? N_NODES : N_HEDGES) - (side ? b * 512 : b * 256);
    if (nrows > NROWS) nrows = NROWS;
    int* srtEb = srtE + (long)b * CAP;
    unsigned short* srtNb = srtN + (long)b * CAP;

    hist[t] = 0;
    __syncthreads();
    for (int i = t; i < cnt_b; i += 512) atomicAdd(&hist[bins[i] >> 17], 1);
    __syncthreads();
    int v = hist[t];
    scanv[t] = v;
    __syncthreads();
    for (int o = 1; o < 512; o <<= 1) {
        int x = (t >= o) ? scanv[t - o] : 0;
        __syncthreads();
        scanv[t] += x;
        __syncthreads();
    }
    int excl = scanv[t] - v;
    if (t < nrows) { off[rowbase + t] = b * CAP + excl; deg[rowbase + t] = v; }
    scanv[t] = excl;
    __syncthreads();
    for (int i = t; i < cnt_b; i += 512) {
        int p = bins[i];
        int pos = atomicAdd(&scanv[p >> 17], 1);
        if (side) srtNb[pos] = (unsigned short)(p & 0x1FFFF);  // hyperedge ids < 25000
        else srtEb[pos] = p & 0x1FFFF;                         // node ids < 100000
    }
}

// ---------------- gather-mean, row-major, 8 lanes/edge x us8 (16B) ----------------
__global__ __launch_bounds__(256) void gather_layer(
    const unsigned short* __restrict__ xnH, const unsigned short* __restrict__ xeH,
    const int* __restrict__ off, const int* __restrict__ deg,
    const int* __restrict__ srtE, const unsigned short* __restrict__ srtN,
    unsigned short* __restrict__ aggEH, unsigned short* __restrict__ aggNH) {
    int lane = threadIdx.x & 63;
    int w = blockIdx.x * 4 + (threadIdx.x >> 6);
    int NW = gridDim.x * 4;
    int sub = lane >> 3;  // 0..7: edge sublane
    int fq = lane & 7;    // us8 chunk (8 feats)
    const int RT = N_HEDGES + N_NODES;
    for (int r = w; r < RT; r += NW) {
        const unsigned short* xsrc; unsigned short* agg; int rr;
        bool eSide = r < N_HEDGES;
        if (eSide) { rr = r; xsrc = xnH; agg = aggEH; }
        else { rr = r - N_HEDGES; xsrc = xeH; agg = aggNH; }
        int lo = off[r];
        int dg = deg[r];
        f4 a0 = {0.f, 0.f, 0.f, 0.f}, a1 = a0, b0 = a0, b1 = a0;
        for (int j0 = 0; j0 < dg; j0 += 64) {
            int chunk = dg - j0;
            if (chunk > 64) chunk = 64;
            int idv;
            if (eSide) idv = (j0 + lane < dg) ? srtE[lo + j0 + lane] : 0;
            else idv = (j0 + lane < dg) ? (int)srtN[lo + j0 + lane] : 0;
            int jj = 0;
            for (; jj + 16 <= chunk; jj += 16) {
                int s0 = __shfl(idv, jj + sub);
                int s1 = __shfl(idv, jj + 8 + sub);
                us8 h0 = *(const us8*)(xsrc + (long)s0 * HD + fq * 8);
                us8 h1 = *(const us8*)(xsrc + (long)s1 * HD + fq * 8);
#pragma unroll
                for (int i = 0; i < 4; i++) {
                    a0[i] += bf2f(h0[i]); a1[i] += bf2f(h0[i + 4]);
                    b0[i] += bf2f(h1[i]); b1[i] += bf2f(h1[i + 4]);
                }
            }
            for (; jj < chunk; jj += 8) {
                int e = jj + sub;
                int s = __shfl(idv, e & 63);
                us8 h = *(const us8*)(xsrc + (long)s * HD + fq * 8);
                if (e < chunk) {
#pragma unroll
                    for (int i = 0; i < 4; i++) { a0[i] += bf2f(h[i]); a1[i] += bf2f(h[i + 4]); }
                }
            }
        }
        a0 += b0; a1 += b1;
#pragma unroll
        for (int m = 8; m <= 32; m <<= 1) {
#pragma unroll
            for (int i = 0; i < 4; i++) {
                a0[i] += __shfl_xor(a0[i], m);
                a1[i] += __shfl_xor(a1[i], m);
            }
        }
        if (sub == 0) {
            float invd = 1.f / (float)(dg > 1 ? dg : 1);
            us4 p0 = f4_to_bf4(a0 * invd), p1 = f4_to_bf4(a1 * invd);
            us8 o;
#pragma unroll
            for (int i = 0; i < 4; i++) { o[i] = p0[i]; o[i + 4] = p1[i]; }
            *(us8*)(agg + (long)rr * HD + fq * 8) = o;
        }
    }
}

// ---------------- combine via MFMA: out = relu([agg|xdst] @ [Wl;Wr] + bl), all bf16 ----------------
__global__ __launch_bounds__(256) void combine_mfma(
    const unsigned short* __restrict__ aggEH, const unsigned short* __restrict__ xeH,
    const unsigned short* __restrict__ aggNH, const unsigned short* __restrict__ xnH,
    const unsigned short* __restrict__ WtE, const float* __restrict__ blE,
    const unsigned short* __restrict__ WtN, const float* __restrict__ blN,
    unsigned short* __restrict__ outEH, unsigned short* __restrict__ outNH, int gbE) {
    __shared__ unsigned short sA[64][136];
    __shared__ unsigned short sW[64][136];
    int t = threadIdx.x;
    const unsigned short *aggH, *xdstH, *Wt;
    const float* bl;
    unsigned short* outH;
    int rows, row0;
    if ((int)blockIdx.x < gbE) {
        aggH = aggEH; xdstH = xeH; Wt = WtE; bl = blE; outH = outEH;
        rows = N_HEDGES; row0 = blockIdx.x * 64;
    } else {
        aggH = aggNH; xdstH = xnH; Wt = WtN; bl = blN; outH = outNH;
        rows = N_NODES; row0 = (blockIdx.x - gbE) * 64;
    }

#pragma unroll
    for (int q = 0; q < 4; q++) {
        int idx = q * 256 + t;
        int c = idx >> 4, ch = idx & 15;
        *(us8*)&sW[c][ch * 8] = *(const us8*)(Wt + c * 128 + ch * 8);
    }
#pragma unroll
    for (int q = 0; q < 4; q++) {
        int idx = q * 256 + t;
        int r = idx >> 4, ch = idx & 15;
        int gr = row0 + r;
        us8 v;
        if (gr < rows) {
            v = (ch < 8) ? *(const us8*)(aggH + (long)gr * HD + ch * 8)
                         : *(const us8*)(xdstH + (long)gr * HD + (ch - 8) * 8);
        } else {
            v = (us8){0, 0, 0, 0, 0, 0, 0, 0};
        }
        *(us8*)&sA[r][ch * 8] = v;
    }
    __syncthreads();

    int lane = t & 63, w = t >> 6;
    int m0 = w * 16;
    int l15 = lane & 15, quad = lane >> 4;
    f4 acc[4];
#pragma unroll
    for (int ct = 0; ct < 4; ct++) {
        float b = bl[ct * 16 + l15];
        acc[ct] = (f4){b, b, b, b};
    }
#pragma unroll
    for (int kb = 0; kb < 4; kb++) {
        s8b a = *(const s8b*)&sA[m0 + l15][kb * 32 + quad * 8];
#pragma unroll
        for (int ct = 0; ct < 4; ct++) {
            s8b bfr = *(const s8b*)&sW[ct * 16 + l15][kb * 32 + quad * 8];
            acc[ct] = __builtin_amdgcn_mfma_f32_16x16x32_bf16(a, bfr, acc[ct], 0, 0, 0);
        }
    }
#pragma unroll
    for (int ct = 0; ct < 4; ct++) {
#pragma unroll
        for (int r = 0; r < 4; r++) {
            int gr = row0 + m0 + quad * 4 + r;
            if (gr < rows) outH[(long)gr * HD + ct * 16 + l15] = f2bf(fmaxf(acc[ct][r], 0.f));
        }
    }
}

// ---------------- parallel pooling from bf16 feats ----------------
__device__ __forceinline__ int lower_bound_dev(const int* arr, int n, int key) {
    int lo = 0, hi = n;
    while (lo < hi) { int mid = (lo + hi) >> 1; if (arr[mid] < key) lo = mid + 1; else hi = mid; }
    return lo;
}

#define PB_N 8
#define PB_E 2
__global__ __launch_bounds__(256) void pool_bf(
    const unsigned short* __restrict__ xnH, const unsigned short* __restrict__ xeH,
    const int* __restrict__ node_batch, const int* __restrict__ edge_batch,
    float* __restrict__ poolN, float* __restrict__ poolE) {
    __shared__ float sp[4][64];
    int b = blockIdx.x;
    const unsigned short* x; const int* batch; float* pool; int n, g, part, P;
    if (b < NG * PB_N) { x = xnH; batch = node_batch; pool = poolN; n = N_NODES; g = b / PB_N; part = b % PB_N; P = PB_N; }
    else { b -= NG * PB_N; x = xeH; batch = edge_batch; pool = poolE; n = N_HEDGES; g = b / PB_E; part = b % PB_E; P = PB_E; }
    int s = lower_bound_dev(batch, n, g);
    int e = lower_bound_dev(batch, n, g + 1);
    int len = e - s;
    int start = s + (int)(((long)len * part) / P);
    int end = s + (int)(((long)len * (part + 1)) / P);
    int lane = threadIdx.x & 63, w = threadIdx.x >> 6;
    int fq = lane & 7, sub = lane >> 3;
    f4 a0 = {0.f, 0.f, 0.f, 0.f}, a1 = a0;
    for (int r = start + w * 8 + sub; r < end; r += 32) {
        us8 h = *(const us8*)(x + (long)r * HD + fq * 8);
#pragma unroll
        for (int c = 0; c < 4; c++) { a0[c] += bf2f(h[c]); a1[c] += bf2f(h[c + 4]); }
    }
#pragma unroll
    for (int c = 0; c < 4; c++) {
        a0[c] += __shfl_xor(a0[c], 8);  a1[c] += __shfl_xor(a1[c], 8);
        a0[c] += __shfl_xor(a0[c], 16); a1[c] += __shfl_xor(a1[c], 16);
        a0[c] += __shfl_xor(a0[c], 32); a1[c] += __shfl_xor(a1[c], 32);
    }
    if (lane < 8) {
        *(f4*)&sp[w][fq * 8] = a0;
        *(f4*)&sp[w][fq * 8 + 4] = a1;
    }
    __syncthreads();
    if (threadIdx.x < 64) {
        int tt = threadIdx.x;
        float v = sp[0][tt] + sp[1][tt] + sp[2][tt] + sp[3][tt];
        if (v != 0.f) atomicAdd(&pool[g * HD + tt], v);
    }
}

// ---------------- final readout (one block per graph) ----------------
__global__ __launch_bounds__(64) void final_readout(
    const float* __restrict__ poolN, const float* __restrict__ poolE,
    const int* __restrict__ node_batch, const int* __restrict__ edge_batch,
    const float* __restrict__ Wout, const float* __restrict__ bout,
    float* __restrict__ out) {
    __shared__ float inv[2];
    int g = blockIdx.x, t = threadIdx.x;
    if (t < 2) {
        const int* arr = t ? edge_batch : node_batch;
        int n = t ? N_HEDGES : N_NODES;
        int lo = lower_bound_dev(arr, n, g);
        int hi = lower_bound_dev(arr, n, g + 1);
        int c = hi - lo;
        inv[t] = 1.f / (float)(c > 1 ? c : 1);
    }
    __syncthreads();
    if (t < 32) {
        float iN = inv[0], iE = inv[1];
        float s = bout[t];
#pragma unroll 8
        for (int k = 0; k < HD; k++)
            s += poolN[g * HD + k] * iN * Wout[k * 32 + t]
               + poolE[g * HD + k] * iE * Wout[(HD + k) * 32 + t];
        out[g * 32 + t] = s;
    }
}

extern "C" void kernel_launch(void* const* d_in, const int* in_sizes, int n_in,
                              void* d_out, int out_size, void* d_ws, size_t ws_size,
                              hipStream_t stream) {
    const float* node_x = (const float*)d_in[0];
    const float* edge_x = (const float*)d_in[1];
    const int* n2e_src = (const int*)d_in[2];
    const int* n2e_dst = (const int*)d_in[3];
    const int* e2n_src = (const int*)d_in[4];
    const int* e2n_dst = (const int*)d_in[5];
    const int* node_batch = (const int*)d_in[6];
    const int* edge_batch = (const int*)d_in[7];
    const float* Wn = (const float*)d_in[8];
    const float* bn = (const float*)d_in[9];
    const float* We = (const float*)d_in[10];
    const float* be = (const float*)d_in[11];
    const float* W1l_n2e = (const float*)d_in[12];
    const float* b1l_n2e = (const float*)d_in[13];
    const float* W1r_n2e = (const float*)d_in[14];
    const float* W1l_e2n = (const float*)d_in[15];
    const float* b1l_e2n = (const float*)d_in[16];
    const float* W1r_e2n = (const float*)d_in[17];
    const float* W2l_n2e = (const float*)d_in[18];
    const float* b2l_n2e = (const float*)d_in[19];
    const float* W2r_n2e = (const float*)d_in[20];
    const float* W2l_e2n = (const float*)d_in[21];
    const float* b2l_e2n = (const float*)d_in[22];
    const float* W2r_e2n = (const float*)d_in[23];
    const float* Wout = (const float*)d_in[24];
    const float* bout = (const float*)d_in[25];
    float* out = (float*)d_out;

    // ---- workspace layout (row-major bf16 features) ----
    unsigned short* AH0 = (unsigned short*)d_ws;        // 6.4M us: xn bf16 -> xn2
    unsigned short* BH0 = AH0 + N_NODES * HD;           // 1.6M: xe -> xe2
    unsigned short* AH1 = BH0 + N_HEDGES * HD;          // 6.4M: xn1
    unsigned short* BH1 = AH1 + N_NODES * HD;           // 1.6M: xe1
    unsigned short* aggNH = BH1 + N_HEDGES * HD;        // 6.4M
    unsigned short* aggEH = aggNH + N_NODES * HD;       // 1.6M
    unsigned short* WtH = aggEH + N_HEDGES * HD;        // 32768 (4 x [64][128])
    float* poolN = (float*)(WtH + 4 * 8192);            // 4096
    float* poolE = poolN + NG * HD;                     // 4096
    int* gcntE = (int*)(poolE + NG * HD);               // 98
    int* gcntN = gcntE + EB_NB;                         // 196
    int* off = gcntN + NB_NB;                           // 125000
    int* deg = off + (N_HEDGES + N_NODES);              // 125000
    int* binE = deg + (N_HEDGES + N_NODES);             // 1,176,000
    int* binN = binE + EB_NB * EB_CAP;                  // 1,215,200
    int* srtE = binN + NB_NB * NB_CAP;                  // 1,176,000 u32
    unsigned short* srtN = (unsigned short*)(srtE + EB_NB * EB_CAP);  // 1,215,200 u16

    const int Bt = 256;

    // 1) prep: Wt conversion + zero pools/cursors (contiguous: poolN..gcntN)
    int zn = 2 * NG * HD + EB_NB + NB_NB;
    prep<<<4 + (zn + Bt - 1) / Bt, Bt, 0, stream>>>(
        W1l_n2e, W1r_n2e, W1l_e2n, W1r_e2n,
        W2l_n2e, W2r_n2e, W2l_e2n, W2r_e2n,
        WtH, (int*)poolN, zn);

    // 2) binning + encoder
    int encBlocks = (ENC_F4 + Bt - 1) / Bt;
    bin_encode<<<2 * TPS + encBlocks, Bt, 0, stream>>>(
        n2e_src, n2e_dst, e2n_src, e2n_dst, binE, binN, gcntE, gcntN,
        node_x, edge_x, Wn, bn, We, be, AH0, BH0);

    // 3) fine CSR fill
    fine_fill<<<EB_NB + NB_NB, 512, 0, stream>>>(binE, binN, gcntE, gcntN,
                                                 off, deg, srtE, srtN);

    int gbE = (N_HEDGES + 63) / 64;  // 391
    int gbN = (N_NODES + 63) / 64;   // 1563
    int gridC = gbE + gbN;

    // 4-5) layer 1
    gather_layer<<<2048, Bt, 0, stream>>>(AH0, BH0, off, deg, srtE, srtN, aggEH, aggNH);
    combine_mfma<<<gridC, Bt, 0, stream>>>(aggEH, BH0, aggNH, AH0,
                                           WtH, b1l_n2e, WtH + 8192, b1l_e2n,
                                           BH1, AH1, gbE);

    // 6-7) layer 2
    gather_layer<<<2048, Bt, 0, stream>>>(AH1, BH1, off, deg, srtE, srtN, aggEH, aggNH);
    combine_mfma<<<gridC, Bt, 0, stream>>>(aggEH, BH1, aggNH, AH1,
                                           WtH + 16384, b2l_n2e, WtH + 24576, b2l_e2n,
                                           BH0, AH0, gbE);

    // 8) pooling
    pool_bf<<<NG * PB_N + NG * PB_E, Bt, 0, stream>>>(AH0, BH0, node_batch, edge_batch, poolN, poolE);

    // 9) readout
    final_readout<<<NG, 64, 0, stream>>>(poolN, poolE, node_batch, edge_batch, Wout, bout, out);
}